// Round 20
// baseline (93.381 us; speedup 1.0000x reference)
//
#include <hip/hip_runtime.h>

typedef __attribute__((ext_vector_type(8))) short short8;   // 8 x bf16
typedef __attribute__((ext_vector_type(4))) float f32x4;
typedef __attribute__((ext_vector_type(4))) unsigned int uint4v;

#define B_SZ 256
#define T_SZ 2048
#define D_SZ 64
#define WAVES 16            // 1024-thread block, one block per batch b
#define TILES 8             // 8 tiles x 16 rows = 128 rows per wave
#define APADH 68            // bf16 slab row stride in shorts (136 B)

// round-half-up to bf16, returned as fp32 bit pattern with low 16 bits zero
__device__ __forceinline__ unsigned int bf16_hi_bits(float f) {
    return (__float_as_uint(f) + 0x8000u) & 0xffff0000u;
}

// Split 8 fp32 into hi (+ optional lo) bf16x8 MFMA A-fragments: x = hi + lo
template <bool LO>
__device__ __forceinline__ void split8(const float4 a, const float4 b,
                                       short8& hi, short8& lo) {
    const float v[8] = {a.x, a.y, a.z, a.w, b.x, b.y, b.z, b.w};
    unsigned int h[4], l[4];
#pragma unroll
    for (int i = 0; i < 8; i += 2) {
        const unsigned int h0 = bf16_hi_bits(v[i]);
        const unsigned int h1 = bf16_hi_bits(v[i + 1]);
        h[i >> 1] = (h0 >> 16) | (h1 & 0xffff0000u);
        if (LO) {
            const float l0 = v[i] - __uint_as_float(h0);
            const float l1 = v[i + 1] - __uint_as_float(h1);
            l[i >> 1] = ((__float_as_uint(l0) + 0x8000u) >> 16) |
                        ((__float_as_uint(l1) + 0x8000u) & 0xffff0000u);
        }
    }
    const uint4v hu = {h[0], h[1], h[2], h[3]};
    hi = __builtin_bit_cast(short8, hu);
    if (LO) {
        const uint4v lu = {l[0], l[1], l[2], l[3]};
        lo = __builtin_bit_cast(short8, lu);
    }
}

// exp(tanh(e)) via tanh = 1 - 2/(1+exp(2e))
__device__ __forceinline__ float exp_tanh(float e) {
    const float u = __expf(2.0f * e);
    const float rr = __builtin_amdgcn_rcpf(1.0f + u);
    return __expf(1.0f - 2.0f * rr);
}

// Build W fragments, h-major: frag f = h*8 + nb*2 + kb (0..7 = hi, 8..15 = lo).
// Lane l holds B[k = kb*32 + (l>>4)*8 + i][n = nb*16 + (l&15)], i=0..7.
__global__ __launch_bounds__(256) void tca_prep(const float* __restrict__ W,
                                                unsigned int* __restrict__ Wf) {
    const int tid = threadIdx.x;
#pragma unroll
    for (int u = 0; u < 4; ++u) {
        const int lf = tid + u * 256;   // 0..1023
        const int f = lf >> 6;
        const int lane = lf & 63;
        const int h = f >> 3;
        const int nb = (f & 7) >> 1;
        const int kb = f & 1;
        const int col = nb * 16 + (lane & 15);
        const int krow = kb * 32 + (lane >> 4) * 8;
        unsigned int d[4];
#pragma unroll
        for (int i = 0; i < 8; i += 2) {
            const float w0 = W[(krow + i) * D_SZ + col];
            const float w1 = W[(krow + i + 1) * D_SZ + col];
            unsigned int b0, b1;
            if (h == 0) {
                b0 = bf16_hi_bits(w0);
                b1 = bf16_hi_bits(w1);
            } else {
                const float l0 = w0 - __uint_as_float(bf16_hi_bits(w0));
                const float l1 = w1 - __uint_as_float(bf16_hi_bits(w1));
                b0 = (__float_as_uint(l0) + 0x8000u) & 0xffff0000u;
                b1 = (__float_as_uint(l1) + 0x8000u) & 0xffff0000u;
            }
            d[i >> 1] = (b0 >> 16) | (b1 & 0xffff0000u);
        }
        const uint4v dv = {d[0], d[1], d[2], d[3]};
        ((uint4v*)Wf)[f * 64 + lane] = dv;
    }
}

// Fused kernel, 2 blocks/CU: Phase 1 hi-matmul colsum -> LDS reduce -> rcpS.
// Phase 2: 3-term matmul, a -> bf16 transpose slab, 1KB-contiguous stores.
__global__ __launch_bounds__(1024, 4) void tca_fused(
        const float* __restrict__ x, const unsigned int* __restrict__ Wf,
        const float* __restrict__ bias, float* __restrict__ out) {
    __shared__ uint4v wf_lds[16 * 64];                  // 16 KB: W hi+lo fragments
    __shared__ unsigned short a_lds[WAVES][16 * APADH]; // 34 KB: bf16 slab
    __shared__ float red[WAVES][64];                    // 4 KB: per-wave colsum
    __shared__ float rcpS_lds[64];

    const int tid = threadIdx.x;
    const int wave = tid >> 6;
    const int lane = tid & 63;
    const int b = blockIdx.x;

    // Stage all 16 W fragments (1024 entries, one per thread).
    wf_lds[tid] = ((const uint4v*)Wf)[tid];
    __syncthreads();

    const int arow = lane & 15;          // A row within 16-row tile
    const int aoff = (lane >> 4) * 8;    // A k-base within 32-block
    const int crow = (lane >> 4) * 4;    // C row base
    const int ccol = lane & 15;          // C col within 16-block
    const int erow = lane >> 4;          // epilogue row within 4-row span
    const int ecol = (lane & 15) * 4;    // epilogue float-col

    const int t_wave = wave * (T_SZ / WAVES);   // 128 rows per wave

    // ---------------- Phase 1: hi-matmul column sums ----------------
    float csum[4] = {0.f, 0.f, 0.f, 0.f};
#pragma unroll 1
    for (int tile = 0; tile < TILES; ++tile) {
        const int t0 = t_wave + tile * 16;
        const float* xrow = x + ((size_t)b * T_SZ + t0 + arow) * D_SZ + aoff;
        const float4 xa0 = *(const float4*)(xrow);
        const float4 xa1 = *(const float4*)(xrow + 4);
        const float4 xb0 = *(const float4*)(xrow + 32);
        const float4 xb1 = *(const float4*)(xrow + 36);

        short8 ah[2], dummy;
        split8<false>(xa0, xa1, ah[0], dummy);
        split8<false>(xb0, xb1, ah[1], dummy);

        f32x4 c[4];
#pragma unroll
        for (int nb = 0; nb < 4; ++nb) {
            f32x4 acc = {0.f, 0.f, 0.f, 0.f};
#pragma unroll
            for (int kb = 0; kb < 2; ++kb) {
                const short8 whf = __builtin_bit_cast(short8, wf_lds[(nb * 2 + kb) * 64 + lane]);
                acc = __builtin_amdgcn_mfma_f32_16x16x32_bf16(ah[kb], whf, acc, 0, 0, 0);
            }
            c[nb] = acc;
        }

        const float* brow = bias + (size_t)(t0 + crow) * D_SZ + ccol;
#pragma unroll
        for (int nb = 0; nb < 4; ++nb)
#pragma unroll
            for (int r = 0; r < 4; ++r)
                csum[nb] += exp_tanh(c[nb][r] + brow[r * D_SZ + nb * 16]);
    }

    // Per-wave reduce to lanes 0..15, park in LDS.
#pragma unroll
    for (int nb = 0; nb < 4; ++nb) {
        float v = csum[nb];
        v += __shfl_xor(v, 16, 64);
        v += __shfl_xor(v, 32, 64);
        if (lane < 16) red[wave][nb * 16 + lane] = v;
    }
    __syncthreads();

    // Block reduce 16 waves -> rcpS (threads 0..63).
    if (tid < 64) {
        float s = 0.f;
#pragma unroll
        for (int w = 0; w < WAVES; ++w) s += red[w][tid];
        rcpS_lds[tid] = __builtin_amdgcn_rcpf(s);
    }
    __syncthreads();

    float rcpS[4];
#pragma unroll
    for (int nb = 0; nb < 4; ++nb)
        rcpS[nb] = rcpS_lds[nb * 16 + ccol];   // same-address broadcast: free

    // ---------------- Phase 2: 3-term matmul + scaled output ----------------
#pragma unroll 1
    for (int tile = 0; tile < TILES; ++tile) {
        const int t0 = t_wave + tile * 16;
        const float* xrow = x + ((size_t)b * T_SZ + t0 + arow) * D_SZ + aoff;
        const float4 xa0 = *(const float4*)(xrow);     // L3-hot re-read
        const float4 xa1 = *(const float4*)(xrow + 4);
        const float4 xb0 = *(const float4*)(xrow + 32);
        const float4 xb1 = *(const float4*)(xrow + 36);

        short8 ah[2], al[2];
        split8<true>(xa0, xa1, ah[0], al[0]);
        split8<true>(xb0, xb1, ah[1], al[1]);

        f32x4 c[4];
#pragma unroll
        for (int nb = 0; nb < 4; ++nb) {
            f32x4 acc = {0.f, 0.f, 0.f, 0.f};
#pragma unroll
            for (int kb = 0; kb < 2; ++kb) {
                const short8 whf = __builtin_bit_cast(short8, wf_lds[(nb * 2 + kb) * 64 + lane]);
                const short8 wlf = __builtin_bit_cast(short8, wf_lds[(8 + nb * 2 + kb) * 64 + lane]);
                acc = __builtin_amdgcn_mfma_f32_16x16x32_bf16(ah[kb], whf, acc, 0, 0, 0);
                acc = __builtin_amdgcn_mfma_f32_16x16x32_bf16(ah[kb], wlf, acc, 0, 0, 0);
                acc = __builtin_amdgcn_mfma_f32_16x16x32_bf16(al[kb], whf, acc, 0, 0, 0);
            }
            c[nb] = acc;
        }

        // a = p * rcpS at C-layout -> bf16 slab (2 lanes/bank: free).
        const float* brow = bias + (size_t)(t0 + crow) * D_SZ + ccol;
#pragma unroll
        for (int nb = 0; nb < 4; ++nb)
#pragma unroll
            for (int r = 0; r < 4; ++r) {
                const float a = exp_tanh(c[nb][r] + brow[r * D_SZ + nb * 16]) * rcpS[nb];
                a_lds[wave][(crow + r) * APADH + nb * 16 + ccol] =
                    (unsigned short)((__float_as_uint(a) + 0x8000u) >> 16);
            }

        // Row-contiguous readback + L1-hot x reload + 1KB-contiguous stores.
        const size_t gbase = ((size_t)b * T_SZ + t0) * D_SZ;
#pragma unroll
        for (int j = 0; j < 4; ++j) {
            const int row = j * 4 + erow;
            const uint2 av = *(const uint2*)&a_lds[wave][row * APADH + ecol];
            const float4 xv = *(const float4*)(x + gbase + row * D_SZ + ecol);
            float4 o;
            o.x = xv.x * __uint_as_float(av.x << 16);
            o.y = xv.y * __uint_as_float(av.x & 0xffff0000u);
            o.z = xv.z * __uint_as_float(av.y << 16);
            o.w = xv.w * __uint_as_float(av.y & 0xffff0000u);
            *(float4*)(out + gbase + row * D_SZ + ecol) = o;
        }
    }
}

extern "C" void kernel_launch(void* const* d_in, const int* in_sizes, int n_in,
                              void* d_out, int out_size, void* d_ws, size_t ws_size,
                              hipStream_t stream) {
    const float* x = (const float*)d_in[0];
    const float* W = (const float*)d_in[1];
    const float* bias = (const float*)d_in[2];
    float* out = (float*)d_out;

    unsigned int* Wf = (unsigned int*)d_ws;   // 16 KB of W fragments

    tca_prep<<<1, 256, 0, stream>>>(W, Wf);
    tca_fused<<<B_SZ, 1024, 0, stream>>>(x, Wf, bias, out);
}

// Round 21
// 90.524 us; speedup vs baseline: 1.0316x; 1.0316x over previous
//
#include <hip/hip_runtime.h>

typedef __attribute__((ext_vector_type(8))) short short8;   // 8 x bf16
typedef __attribute__((ext_vector_type(4))) float f32x4;
typedef __attribute__((ext_vector_type(4))) unsigned int uint4v;

#define B_SZ 256
#define T_SZ 2048
#define D_SZ 64
#define TILES_PER_WAVE 4   // 16 rows each -> 64 rows per wave
#define SEGS 8             // blocks per b; 4 waves * 64 rows * 8 = 2048 rows
#define APAD 68            // transpose slab row stride in dwords

// round-half-up to bf16, returned as fp32 bit pattern with low 16 bits zero
__device__ __forceinline__ unsigned int bf16_hi_bits(float f) {
    return (__float_as_uint(f) + 0x8000u) & 0xffff0000u;
}

// Split 8 fp32 into hi (+ optional lo) bf16x8 MFMA A-fragments: x = hi + lo
template <bool LO>
__device__ __forceinline__ void split8(const float4 a, const float4 b,
                                       short8& hi, short8& lo) {
    const float v[8] = {a.x, a.y, a.z, a.w, b.x, b.y, b.z, b.w};
    unsigned int h[4], l[4];
#pragma unroll
    for (int i = 0; i < 8; i += 2) {
        const unsigned int h0 = bf16_hi_bits(v[i]);
        const unsigned int h1 = bf16_hi_bits(v[i + 1]);
        h[i >> 1] = (h0 >> 16) | (h1 & 0xffff0000u);
        if (LO) {
            const float l0 = v[i] - __uint_as_float(h0);
            const float l1 = v[i + 1] - __uint_as_float(h1);
            l[i >> 1] = ((__float_as_uint(l0) + 0x8000u) >> 16) |
                        ((__float_as_uint(l1) + 0x8000u) & 0xffff0000u);
        }
    }
    const uint4v hu = {h[0], h[1], h[2], h[3]};
    hi = __builtin_bit_cast(short8, hu);
    if (LO) {
        const uint4v lu = {l[0], l[1], l[2], l[3]};
        lo = __builtin_bit_cast(short8, lu);
    }
}

// exp(tanh(e)) via tanh = 1 - 2/(1+exp(2e))
__device__ __forceinline__ float exp_tanh(float e) {
    const float u = __expf(2.0f * e);
    const float rr = __builtin_amdgcn_rcpf(1.0f + u);
    return __expf(1.0f - 2.0f * rr);
}

// Grid of 16 blocks: every block zeroes its 4 KB slice of S; block 0 also
// builds W fragments, h-major: frag f = h*8 + nb*2 + kb  (0..7 = hi, 8..15 = lo).
// Lane l holds B[k = kb*32 + (l>>4)*8 + i][n = nb*16 + (l&15)], i=0..7.
__global__ __launch_bounds__(256) void tca_prep(const float* __restrict__ W,
                                                unsigned int* __restrict__ Wf,
                                                float* __restrict__ S) {
    const int tid = threadIdx.x;
    const float4 z = make_float4(0.f, 0.f, 0.f, 0.f);
    ((float4*)S)[blockIdx.x * 256 + tid] = z;   // 16 blocks * 4 KB = 64 KB

    if (blockIdx.x != 0) return;
#pragma unroll
    for (int u = 0; u < 4; ++u) {
        const int lf = tid + u * 256;   // 0..1023
        const int f = lf >> 6;
        const int lane = lf & 63;
        const int h = f >> 3;
        const int nb = (f & 7) >> 1;
        const int kb = f & 1;
        const int col = nb * 16 + (lane & 15);
        const int krow = kb * 32 + (lane >> 4) * 8;
        unsigned int d[4];
#pragma unroll
        for (int i = 0; i < 8; i += 2) {
            const float w0 = W[(krow + i) * D_SZ + col];
            const float w1 = W[(krow + i + 1) * D_SZ + col];
            unsigned int b0, b1;
            if (h == 0) {
                b0 = bf16_hi_bits(w0);
                b1 = bf16_hi_bits(w1);
            } else {
                const float l0 = w0 - __uint_as_float(bf16_hi_bits(w0));
                const float l1 = w1 - __uint_as_float(bf16_hi_bits(w1));
                b0 = (__float_as_uint(l0) + 0x8000u) & 0xffff0000u;
                b1 = (__float_as_uint(l1) + 0x8000u) & 0xffff0000u;
            }
            d[i >> 1] = (b0 >> 16) | (b1 & 0xffff0000u);
        }
        const uint4v dv = {d[0], d[1], d[2], d[3]};
        ((uint4v*)Wf)[f * 64 + lane] = dv;
    }
}

// k1: S[b][d] += column sums of exp(tanh(x@W + bias)), hi-term matmul only.
// Slim: 8 KB LDS, no stores, 8 waves/SIMD.
__global__ __launch_bounds__(256, 8) void tca_colsum(
        const float* __restrict__ x, const unsigned int* __restrict__ Wf,
        const float* __restrict__ bias, float* __restrict__ S) {
    __shared__ uint4v wf_lds[8 * 64];   // 8 KB: W-hi fragments

    const int tid = threadIdx.x;
    const int wave = tid >> 6;
    const int lane = tid & 63;
    const int b = blockIdx.x >> 3;
    const int seg = blockIdx.x & (SEGS - 1);

#pragma unroll
    for (int q = 0; q < 2; ++q)
        wf_lds[tid + q * 256] = ((const uint4v*)Wf)[tid + q * 256];
    __syncthreads();

    const int arow = lane & 15;
    const int aoff = (lane >> 4) * 8;
    const int crow = (lane >> 4) * 4;
    const int ccol = lane & 15;

    float csum[4] = {0.f, 0.f, 0.f, 0.f};
    const int t_wave = seg * 256 + wave * 64;

#pragma unroll 1
    for (int tile = 0; tile < TILES_PER_WAVE; ++tile) {
        const int t0 = t_wave + tile * 16;
        const float* xrow = x + ((size_t)b * T_SZ + t0 + arow) * D_SZ + aoff;
        const float4 xa0 = *(const float4*)(xrow);
        const float4 xa1 = *(const float4*)(xrow + 4);
        const float4 xb0 = *(const float4*)(xrow + 32);
        const float4 xb1 = *(const float4*)(xrow + 36);

        short8 ah[2], dummy;
        split8<false>(xa0, xa1, ah[0], dummy);
        split8<false>(xb0, xb1, ah[1], dummy);

        f32x4 c[4];
#pragma unroll
        for (int nb = 0; nb < 4; ++nb) {
            f32x4 acc = {0.f, 0.f, 0.f, 0.f};
#pragma unroll
            for (int kb = 0; kb < 2; ++kb) {
                const short8 whf = __builtin_bit_cast(short8, wf_lds[(nb * 2 + kb) * 64 + lane]);
                acc = __builtin_amdgcn_mfma_f32_16x16x32_bf16(ah[kb], whf, acc, 0, 0, 0);
            }
            c[nb] = acc;
        }

        const float* brow = bias + (size_t)(t0 + crow) * D_SZ + ccol;
#pragma unroll
        for (int nb = 0; nb < 4; ++nb)
#pragma unroll
            for (int r = 0; r < 4; ++r)
                csum[nb] += exp_tanh(c[nb][r] + brow[r * D_SZ + nb * 16]);
    }

#pragma unroll
    for (int nb = 0; nb < 4; ++nb) {
        float v = csum[nb];
        v += __shfl_xor(v, 16, 64);
        v += __shfl_xor(v, 32, 64);
        if (lane < 16) atomicAdd(&S[b * D_SZ + nb * 16 + lane], v);
    }
}

// k2: out = x * exp(tanh(x@W + bias)) * rcp(S), 3-term matmul.
// Epilogue: per-wave LDS transpose slab; readback + x reload + store all at
// ROW-CONTIGUOUS layout (row = j*4 + lane>>4, col = (lane&15)*4) so each
// store instruction writes 1 KB fully contiguous (8 complete 128B sectors).
__global__ __launch_bounds__(256, 4) void tca_out(
        const float* __restrict__ x, const unsigned int* __restrict__ Wf,
        const float* __restrict__ bias, const float* __restrict__ S,
        float* __restrict__ out) {
    __shared__ uint4v wf_lds[16 * 64];      // 16 KB: W hi+lo fragments
    __shared__ float a_lds[4][16 * APAD];   // 17.4 KB: per-wave transpose slab

    const int tid = threadIdx.x;
    const int wave = tid >> 6;
    const int lane = tid & 63;
    const int b = blockIdx.x >> 3;
    const int seg = blockIdx.x & (SEGS - 1);

#pragma unroll
    for (int q = 0; q < 4; ++q)
        wf_lds[tid + q * 256] = ((const uint4v*)Wf)[tid + q * 256];
    __syncthreads();

    const int arow = lane & 15;
    const int aoff = (lane >> 4) * 8;
    const int crow = (lane >> 4) * 4;
    const int ccol = lane & 15;
    const int erow = lane >> 4;          // epilogue row within 4-row span
    const int ecol = (lane & 15) * 4;    // epilogue float-col

    float rcpS[4];
#pragma unroll
    for (int nb = 0; nb < 4; ++nb)
        rcpS[nb] = __builtin_amdgcn_rcpf(S[b * D_SZ + nb * 16 + ccol]);

    const int t_wave = seg * 256 + wave * 64;

#pragma unroll 1
    for (int tile = 0; tile < TILES_PER_WAVE; ++tile) {
        const int t0 = t_wave + tile * 16;
        const float* xrow = x + ((size_t)b * T_SZ + t0 + arow) * D_SZ + aoff;
        const float4 xa0 = *(const float4*)(xrow);
        const float4 xa1 = *(const float4*)(xrow + 4);
        const float4 xb0 = *(const float4*)(xrow + 32);
        const float4 xb1 = *(const float4*)(xrow + 36);

        short8 ah[2], al[2];
        split8<true>(xa0, xa1, ah[0], al[0]);
        split8<true>(xb0, xb1, ah[1], al[1]);

        f32x4 c[4];
#pragma unroll
        for (int nb = 0; nb < 4; ++nb) {
            f32x4 acc = {0.f, 0.f, 0.f, 0.f};
#pragma unroll
            for (int kb = 0; kb < 2; ++kb) {
                const short8 whf = __builtin_bit_cast(short8, wf_lds[(nb * 2 + kb) * 64 + lane]);
                const short8 wlf = __builtin_bit_cast(short8, wf_lds[(8 + nb * 2 + kb) * 64 + lane]);
                acc = __builtin_amdgcn_mfma_f32_16x16x32_bf16(ah[kb], whf, acc, 0, 0, 0);
                acc = __builtin_amdgcn_mfma_f32_16x16x32_bf16(ah[kb], wlf, acc, 0, 0, 0);
                acc = __builtin_amdgcn_mfma_f32_16x16x32_bf16(al[kb], whf, acc, 0, 0, 0);
            }
            c[nb] = acc;
        }

        // a = p * rcpS at C-layout -> wave-private transpose slab.
        const float* brow = bias + (size_t)(t0 + crow) * D_SZ + ccol;
#pragma unroll
        for (int nb = 0; nb < 4; ++nb)
#pragma unroll
            for (int r = 0; r < 4; ++r)
                a_lds[wave][(crow + r) * APAD + nb * 16 + ccol] =
                    exp_tanh(c[nb][r] + brow[r * D_SZ + nb * 16]) * rcpS[nb];

        // Row-contiguous readback/store: 4 insts x (4 rows x 256B contiguous).
        // x reload is L1/L2-hot (this block just loaded these lines).
        const size_t gbase = ((size_t)b * T_SZ + t0) * D_SZ;
#pragma unroll
        for (int j = 0; j < 4; ++j) {
            const int row = j * 4 + erow;
            const float4 av = *(const float4*)&a_lds[wave][row * APAD + ecol];
            const float4 xv = *(const float4*)(x + gbase + row * D_SZ + ecol);
            float4 o;
            o.x = xv.x * av.x; o.y = xv.y * av.y;
            o.z = xv.z * av.z; o.w = xv.w * av.w;
            *(float4*)(out + gbase + row * D_SZ + ecol) = o;
        }
    }
}

extern "C" void kernel_launch(void* const* d_in, const int* in_sizes, int n_in,
                              void* d_out, int out_size, void* d_ws, size_t ws_size,
                              hipStream_t stream) {
    const float* x = (const float*)d_in[0];
    const float* W = (const float*)d_in[1];
    const float* bias = (const float*)d_in[2];
    float* out = (float*)d_out;

    unsigned int* Wf = (unsigned int*)d_ws;   // 16 KB of W fragments
    float* S = (float*)d_ws + 4096;           // B*D floats = 64 KB

    tca_prep<<<16, 256, 0, stream>>>(W, Wf, S);   // zeroes S + builds Wf

    const dim3 grid(B_SZ * SEGS);   // 2048 blocks
    const dim3 block(256);
    tca_colsum<<<grid, block, 0, stream>>>(x, Wf, bias, S);
    tca_out<<<grid, block, 0, stream>>>(x, Wf, bias, S, out);
}